// Round 1
// 213.378 us; speedup vs baseline: 1.2487x; 1.2487x over previous
//
#include <hip/hip_runtime.h>

// RAConv: reciprocal-attention graph conv, N=100K nodes, E=1.6M edges, D=64, fp32.
// CSR build -> wave-per-node register gather -> bf16 MFMA GEMM.
//   msg = (sum_e x_src*exp(logit)) / (sum_e exp(logit));  var = E[x^2]-E[x]^2
// R2-R10: see git log (split-half gather, MFMA gemm, XCD partition, bf16
//        datapath, rank-recording hist, atomic-free scatter, pipelined loads,
//        pk-fp32 accum, 4-way scatter partitions, fused cast+hist).
// R11: global-atomic-free CSR build. Old hist did 1.6M returning device-scope
//      atomicAdds at ~23G/s (70us, 32B write-through each, WRITE_SIZE 68MB).
//      Replaced by 2-level bucket sort with LDS atomics only:
//        hist (per-4096-edge-chunk LDS hist over dst>>8 buckets, cast fused)
//        -> 2-level scan (bucket-major) -> partition (LDS-rank, packed
//        (src<<8)|dst&255 into bucket segments) -> per-bucket fine sort
//        (256 nodes/block, LDS hist+scan, writes rs + srcs directly).
//      deg/rank buffers and the deg memset are gone.

static inline size_t ws_align(size_t x) { return (x + 255) & ~size_t(255); }

typedef __attribute__((ext_vector_type(8))) short bf16x8;
typedef __attribute__((ext_vector_type(4))) float f32x4;
typedef __attribute__((ext_vector_type(2))) float f32x2;

#define ECHUNK 4096   // edges per histogram/partition block

__device__ __forceinline__ unsigned short f2bf(float f) {
    unsigned u = __builtin_bit_cast(unsigned, f);
    u += 0x7FFFu + ((u >> 16) & 1u);          // RNE
    return (unsigned short)(u >> 16);
}
__device__ __forceinline__ float bfhi(int d) {          // high bf16 of dword
    return __builtin_bit_cast(float, (unsigned)d & 0xFFFF0000u);
}
__device__ __forceinline__ float bflo(int d) {          // low bf16 of dword
    return __builtin_bit_cast(float, (unsigned)d << 16);
}

// Fused: cast x->bf16 (grid-stride) AND per-chunk LDS histogram over coarse
// buckets (dst>>8). Block b owns edges [b*ECHUNK, (b+1)*ECHUNK); writes
// hist[bucket*nblk + b] (bucket-major so bucket segments are contiguous
// after the scan). No global atomics.
__global__ void __launch_bounds__(256) hist_cast_kernel(
        const float* __restrict__ x, unsigned short* __restrict__ xb,
        const int* __restrict__ ei, int* __restrict__ hist,
        int E, int n4, int nblk, int nb1) {
    __shared__ int h[512];                       // nb1 <= 512 (N <= 131072)
    for (int k = threadIdx.x; k < nb1; k += 256) h[k] = 0;
    // cast part: grid-stride over n4 float4s
    int stride = gridDim.x * 256;
    for (int i = blockIdx.x * 256 + threadIdx.x; i < n4; i += stride) {
        float4 v = ((const float4*)x)[i];
        ushort4 hh; hh.x = f2bf(v.x); hh.y = f2bf(v.y); hh.z = f2bf(v.z); hh.w = f2bf(v.w);
        ((ushort4*)xb)[i] = hh;
    }
    __syncthreads();
    const int* dstp = ei + E;
    int base = blockIdx.x * ECHUNK;
    #pragma unroll 4
    for (int k = 0; k < ECHUNK / 256; ++k) {
        int e = base + k * 256 + threadIdx.x;
        if (e < E) atomicAdd(&h[dstp[e] >> 8], 1);
    }
    __syncthreads();
    for (int k = threadIdx.x; k < nb1; k += 256) hist[k * nblk + blockIdx.x] = h[k];
}

// Exclusive scan over M = nb1*nblk counts, in place, 256/block; block sums out.
__global__ void scan_a_kernel(int* __restrict__ h, int* __restrict__ bsum, int M) {
    __shared__ int t[256];
    int i = blockIdx.x * 256 + threadIdx.x;
    int v = (i < M) ? h[i] : 0;
    t[threadIdx.x] = v;
    __syncthreads();
    for (int off = 1; off < 256; off <<= 1) {
        int u = (threadIdx.x >= (unsigned)off) ? t[threadIdx.x - off] : 0;
        __syncthreads();
        t[threadIdx.x] += u;
        __syncthreads();
    }
    if (i < M) h[i] = t[threadIdx.x] - v;        // exclusive within block
    if (threadIdx.x == 255) bsum[blockIdx.x] = t[255];
}

// Exclusive scan of block sums (nb <= 1024). Consumers add bsum[idx>>8].
__global__ void scan_b_kernel(int* __restrict__ bsum, int nb) {
    __shared__ int t[1024];
    int i = threadIdx.x;
    int v = (i < nb) ? bsum[i] : 0;
    t[i] = v;
    __syncthreads();
    for (int off = 1; off < 1024; off <<= 1) {
        int u = (i >= off) ? t[i - off] : 0;
        __syncthreads();
        t[i] += u;
        __syncthreads();
    }
    if (i < nb) bsum[i] = t[i] - v;             // exclusive
}

// Partition edges into coarse-bucket segments. Block b re-reads its chunk,
// ranks via LDS atomics on its scanned offsets, writes packed
// (src<<8)|(dst&255) -- src < 2^17, key 8 bits -> fits int.
__global__ void __launch_bounds__(256) part_kernel(
        const int* __restrict__ ei, const int* __restrict__ offs,
        const int* __restrict__ bsum, int* __restrict__ tmp,
        int E, int nblk, int nb1) {
    __shared__ int lofs[512];
    int b = blockIdx.x;
    for (int k = threadIdx.x; k < nb1; k += 256) {
        int idx = k * nblk + b;
        lofs[k] = offs[idx] + bsum[idx >> 8];
    }
    __syncthreads();
    const int* dstp = ei + E;
    int base = b * ECHUNK;
    #pragma unroll 4
    for (int k = 0; k < ECHUNK / 256; ++k) {
        int e = base + k * 256 + threadIdx.x;
        if (e < E) {
            int dst = dstp[e];
            int src = ei[e];
            int pos = atomicAdd(&lofs[dst >> 8], 1);
            tmp[pos] = (src << 8) | (dst & 255);
        }
    }
}

// Per-bucket fine sort: one block per bucket (256 nodes <-> 256 threads).
// LDS 256-bin hist + scan -> writes rs[node] directly, scatters srcs in CSR
// order via LDS-atomic ranks.
__global__ void __launch_bounds__(256) fsort_kernel(
        const int* __restrict__ tmp, const int* __restrict__ offs,
        const int* __restrict__ bsum, int* __restrict__ srcs,
        int* __restrict__ rs, int E, int N, int nblk, int nb1) {
    __shared__ int cnt[256], sc[256], lofs[256];
    int b = blockIdx.x, tid = threadIdx.x;
    int i0 = b * nblk;
    int start = offs[i0] + bsum[i0 >> 8];
    int end;
    if (b == nb1 - 1) end = E;
    else { int i1 = (b + 1) * nblk; end = offs[i1] + bsum[i1 >> 8]; }

    cnt[tid] = 0;
    __syncthreads();
    for (int e = start + tid; e < end; e += 256) atomicAdd(&cnt[tmp[e] & 255], 1);
    __syncthreads();
    int c = cnt[tid];
    sc[tid] = c;
    __syncthreads();
    for (int off = 1; off < 256; off <<= 1) {
        int u = (tid >= off) ? sc[tid - off] : 0;
        __syncthreads();
        sc[tid] += u;
        __syncthreads();
    }
    int excl = sc[tid] - c;
    int node = b * 256 + tid;
    if (node < N) rs[node] = start + excl;
    lofs[tid] = start + excl;
    __syncthreads();
    for (int e = start + tid; e < end; e += 256) {
        int v = tmp[e];
        int pos = atomicAdd(&lofs[v & 255], 1);
        srcs[pos] = v >> 8;
    }
    if (b == 0 && tid == 0) rs[N] = E;
}

// One wave per node, 4 edges per batch: 16-lane group g handles edge srcs[p+g],
// lane q=lane&15 holds features 4q..4q+3 as two float2 (packed-fp32 ALU path).
// xn read from xb (bf16): logit is bf16*bf16 -> fp32.
__global__ void __launch_bounds__(256) node_gather_kernel(
        const unsigned short* __restrict__ xb,
        const int* __restrict__ rs, const int* __restrict__ srcs,
        unsigned short* __restrict__ msgvar, int N) {
    int w = (blockIdx.x * blockDim.x + threadIdx.x) >> 6;
    if (w >= N) return;
    int lane = threadIdx.x & 63;
    int q = lane & 15;                 // feature block (features 4q..4q+3)
    int g = lane >> 4;                 // edge slot within batch of 4
    int s = rs[w], e = rs[w + 1];
    const int2* xb2 = (const int2*)xb;            // row = 16 int2 (128 B)
    int2 dn = xb2[(size_t)w * 16 + q];
    f32x2 xn01 = {bflo(dn.x), bfhi(dn.x)}, xn23 = {bflo(dn.y), bfhi(dn.y)};
    float den = 0.f;
    f32x2 sxa = {0,0}, sxb = {0,0}, ssqa = {0,0}, ssqb = {0,0},
          smea = {0,0}, smeb = {0,0};

    auto compute = [&](int2 d) {
        f32x2 a = {bflo(d.x), bfhi(d.x)};
        f32x2 b = {bflo(d.y), bfhi(d.y)};
        f32x2 dp = a * xn01 + b * xn23;           // pk mul + pk fma
        float t = dp.x + dp.y;
        #pragma unroll
        for (int off = 1; off < 16; off <<= 1) t += __shfl_xor(t, off, 64);
        float ex = __expf(t * 0.125f);
        f32x2 ex2 = {ex, ex};
        den += ex;
        sxa += a;           sxb += b;             // pk add
        ssqa += a * a;      ssqb += b * b;        // pk fma
        smea += ex2 * a;    smeb += ex2 * b;      // pk fma
    };

    int p = s;
    for (; p + 8 <= e; p += 8) {                  // 2 batches, pipelined
        int ra = srcs[p + g];
        int rb = srcs[p + 4 + g];
        int2 da = xb2[(size_t)ra * 16 + q];
        int2 db = xb2[(size_t)rb * 16 + q];
        compute(da);
        compute(db);
    }
    if (p + 4 <= e) {
        int r = srcs[p + g];
        compute(xb2[(size_t)r * 16 + q]);
        p += 4;
    }
    if (p < e) {                                  // masked tail (1-3 edges)
        float wt = (p + g < e) ? 1.f : 0.f;
        int r = srcs[min(p + g, e - 1)];
        int2 d = xb2[(size_t)r * 16 + q];
        f32x2 a = {bflo(d.x), bfhi(d.x)};
        f32x2 b = {bflo(d.y), bfhi(d.y)};
        f32x2 dp = a * xn01 + b * xn23;
        float t = dp.x + dp.y;
        #pragma unroll
        for (int off = 1; off < 16; off <<= 1) t += __shfl_xor(t, off, 64);
        float ex = __expf(t * 0.125f) * wt;
        f32x2 wt2 = {wt, wt}, ex2 = {ex, ex};
        f32x2 wa = a * wt2, wb = b * wt2;
        den += ex;
        sxa += wa;          sxb += wb;
        ssqa += wa * a;     ssqb += wb * b;
        smea += ex2 * a;    smeb += ex2 * b;
    }
    // combine the 4 groups (lanes q, q+16, q+32, q+48 hold the same features)
    #pragma unroll
    for (int off = 16; off < 64; off <<= 1) {
        den    += __shfl_xor(den,    off, 64);
        sxa.x  += __shfl_xor(sxa.x,  off, 64); sxa.y  += __shfl_xor(sxa.y,  off, 64);
        sxb.x  += __shfl_xor(sxb.x,  off, 64); sxb.y  += __shfl_xor(sxb.y,  off, 64);
        ssqa.x += __shfl_xor(ssqa.x, off, 64); ssqa.y += __shfl_xor(ssqa.y, off, 64);
        ssqb.x += __shfl_xor(ssqb.x, off, 64); ssqb.y += __shfl_xor(ssqb.y, off, 64);
        smea.x += __shfl_xor(smea.x, off, 64); smea.y += __shfl_xor(smea.y, off, 64);
        smeb.x += __shfl_xor(smeb.x, off, 64); smeb.y += __shfl_xor(smeb.y, off, 64);
    }
    if (lane < 16) {
        float inv = 1.f / fmaxf((float)(e - s), 1.f);
        float invden = (den > 0.f) ? (1.f / den) : 0.f;
        float m0 = sxa.x * inv, m1 = sxa.y * inv, m2 = sxb.x * inv, m3 = sxb.y * inv;
        ushort4 hm, hv;
        hm.x = f2bf(smea.x * invden); hm.y = f2bf(smea.y * invden);
        hm.z = f2bf(smeb.x * invden); hm.w = f2bf(smeb.y * invden);
        hv.x = f2bf(ssqa.x * inv - m0 * m0); hv.y = f2bf(ssqa.y * inv - m1 * m1);
        hv.z = f2bf(ssqb.x * inv - m2 * m2); hv.w = f2bf(ssqb.y * inv - m3 * m3);
        *(ushort4*)&msgvar[(size_t)w * 128 + 4 * q]      = hm;
        *(ushort4*)&msgvar[(size_t)w * 128 + 64 + 4 * q] = hv;
    }
}

// MFMA epilogue GEMM: out = A @ Wcat^T + b, A = [x | msg | var] (N x 192),
// all inputs already bf16 (xb, msgvar). 2 node-tiles of 64 per block with
// W-fragments and bias resident in registers across tiles.
__global__ void __launch_bounds__(256) gemm_kernel(
        const unsigned short* __restrict__ xb, const unsigned short* __restrict__ msgvar,
        const float* __restrict__ Ws, const float* __restrict__ bs,
        const float* __restrict__ Wn, const float* __restrict__ bn,
        const float* __restrict__ Wv, const float* __restrict__ bv,
        float* __restrict__ out, int N) {
    __shared__ unsigned short As[64 * 200];
    int tid = threadIdx.x;
    int lane = tid & 63;
    int wv = tid >> 6;                  // feature tile (wave id)
    int j = lane & 15, quad = lane >> 4;
    int jg = wv * 16 + j;               // global output feature

    // B fragments: 6 K-steps, lane holds W[jg][k0..k0+7] as bf16
    const float* Wm0[3] = {Ws, Wn, Wv};
    bf16x8 bfrag[6];
    #pragma unroll
    for (int ks = 0; ks < 6; ++ks) {
        const float* W = Wm0[ks >> 1];
        int k0 = (ks & 1) * 32 + quad * 8;
        const float4* p = (const float4*)(W + (size_t)jg * 64 + k0);
        float4 a = p[0], b = p[1];
        bf16x8 f;
        f[0] = (short)f2bf(a.x); f[1] = (short)f2bf(a.y);
        f[2] = (short)f2bf(a.z); f[3] = (short)f2bf(a.w);
        f[4] = (short)f2bf(b.x); f[5] = (short)f2bf(b.y);
        f[6] = (short)f2bf(b.z); f[7] = (short)f2bf(b.w);
        bfrag[ks] = f;
    }
    float bias = bs[jg] + bn[jg] + bv[jg];

    #pragma unroll
    for (int t = 0; t < 2; ++t) {
        int nbase = blockIdx.x * 128 + t * 64;
        // stage x part from xb: 64 rows x 16 ushort4 (bf16 direct copy)
        #pragma unroll
        for (int i = 0; i < 4; ++i) {
            int idx = i * 256 + tid;
            int row = idx >> 4, c = idx & 15;
            int n = min(nbase + row, N - 1);
            ushort4 h = ((const ushort4*)(xb + (size_t)n * 64))[c];
            *(ushort4*)&As[row * 200 + c * 4] = h;
        }
        // stage msgvar part: 64 rows x 32 ushort4 (bf16, [msg|var] contiguous)
        #pragma unroll
        for (int i = 0; i < 8; ++i) {
            int idx = i * 256 + tid;
            int row = idx >> 5, c = idx & 31;
            int n = min(nbase + row, N - 1);
            ushort4 h = ((const ushort4*)(msgvar + (size_t)n * 128))[c];
            *(ushort4*)&As[row * 200 + 64 + c * 4] = h;
        }
        __syncthreads();

        f32x4 acc[4];
        #pragma unroll
        for (int nt = 0; nt < 4; ++nt) {
            acc[nt][0] = bias; acc[nt][1] = bias; acc[nt][2] = bias; acc[nt][3] = bias;
        }
        #pragma unroll
        for (int nt = 0; nt < 4; ++nt) {
            #pragma unroll
            for (int ks = 0; ks < 6; ++ks) {
                const bf16x8* ap = (const bf16x8*)&As[(nt * 16 + j) * 200 + ks * 32 + quad * 8];
                acc[nt] = __builtin_amdgcn_mfma_f32_16x16x32_bf16(*ap, bfrag[ks], acc[nt], 0, 0, 0);
            }
        }
        // D: node = nbase + nt*16 + quad*4 + r, col = jg
        #pragma unroll
        for (int nt = 0; nt < 4; ++nt) {
            #pragma unroll
            for (int r = 0; r < 4; ++r) {
                int node = nbase + nt * 16 + quad * 4 + r;
                if (node < N) out[(size_t)node * 64 + jg] = acc[nt][r];
            }
        }
        __syncthreads();   // protect As before next tile's staging
    }
}

extern "C" void kernel_launch(void* const* d_in, const int* in_sizes, int n_in,
                              void* d_out, int out_size, void* d_ws, size_t ws_size,
                              hipStream_t stream) {
    const float* x  = (const float*)d_in[0];
    const int*   ei = (const int*)d_in[1];
    const float* Ws = (const float*)d_in[2];
    const float* bs = (const float*)d_in[3];
    const float* Wn = (const float*)d_in[4];
    const float* bn = (const float*)d_in[5];
    const float* Wv = (const float*)d_in[6];
    const float* bv = (const float*)d_in[7];
    float* out = (float*)d_out;

    int N  = in_sizes[0] / 64;
    int E  = in_sizes[1] / 2;
    int nblk = (E + ECHUNK - 1) / ECHUNK;        // edge chunks (hist blocks)
    int nb1  = (N + 255) >> 8;                   // coarse buckets (<= 512)
    int M    = nb1 * nblk;                       // scan length
    int NBs  = (M + 255) / 256;                  // scan_a blocks (<= 1024)

    char* wsp = (char*)d_ws;
    size_t off = 0;
    int* hist   = (int*)(wsp + off); off += ws_align((size_t)M * 4);
    int* bsumi  = (int*)(wsp + off); off += ws_align((size_t)NBs * 4);
    int* rs     = (int*)(wsp + off); off += ws_align((size_t)(N + 1) * 4);
    int* tmp    = (int*)(wsp + off); off += ws_align((size_t)E * 4);
    int* srcs   = (int*)(wsp + off); off += ws_align((size_t)E * 4);
    unsigned short* msgvar = (unsigned short*)(wsp + off); off += ws_align((size_t)N * 128 * 2);
    unsigned short* xb     = (unsigned short*)(wsp + off); off += ws_align((size_t)N * 64 * 2);

    int n4 = N * 16;
    hist_cast_kernel<<<nblk, 256, 0, stream>>>(x, xb, ei, hist, E, n4, nblk, nb1);
    scan_a_kernel<<<NBs, 256, 0, stream>>>(hist, bsumi, M);
    scan_b_kernel<<<1, 1024, 0, stream>>>(bsumi, NBs);
    part_kernel<<<nblk, 256, 0, stream>>>(ei, hist, bsumi, tmp, E, nblk, nb1);
    fsort_kernel<<<nb1, 256, 0, stream>>>(tmp, hist, bsumi, srcs, rs, E, N, nblk, nb1);
    node_gather_kernel<<<((size_t)N * 64 + 255) / 256, 256, 0, stream>>>(xb, rs, srcs, msgvar, N);
    gemm_kernel<<<(N + 127) / 128, 256, 0, stream>>>(xb, msgvar, Ws, bs, Wn, bn, Wv, bv, out, N);
}